// Round 7
// baseline (83.165 us; speedup 1.0000x reference)
//
#include <hip/hip_runtime.h>
#include <math.h>

#define BB 16
#define SS 2048
#define HH 2
#define NIH 8                 // key-range splits (occupancy)
#define KCHUNK (SS / NIH)     // 256 keys per block
#define RPB 128               // rows per block = 4 waves x 32
#define THREADS 256
#define NITER (KCHUNK / 32)   // 8
#define KVT_STRIDE 264        // 256 + 8 halves pad: row stride 528B (16B-aligned, 4-bank skew)

typedef _Float16 half8 __attribute__((ext_vector_type(8)));
typedef _Float16 half2h __attribute__((ext_vector_type(2)));
typedef float floatx16 __attribute__((ext_vector_type(16)));

__device__ __forceinline__ float fast_exp2(float x) {
  return __builtin_amdgcn_exp2f(x);
}
__device__ __forceinline__ half2h pkrtz(float a, float b) {
  return __builtin_bit_cast(half2h, __builtin_amdgcn_cvt_pkrtz(a, b));
}

// grid: [ih(8)][bh(32)][rb(16)] = 4096 blocks of 256 thr (4 waves x 32 rows).
// Each block: keys [ih*256, +256) x rows [rb*128, +128) of one (b,h).
// QK via 32x32x16 MFMA (32 keys x 32 rows / instr); exp on VALU; PV via two
// K=16 32x32x16 MFMAs whose A-operand is exactly the post-exp registers,
// thanks to storing kv^T in permuted key order (swap bits 2<->3 of pos&15).
// Ones-row in kv^T yields the softmax denominator as output column 4.
// Writes disjoint unnormalized partials (o[4], l) to ws[ih][bh][row][8].
__global__ __launch_bounds__(THREADS, 8)
void qattn_part(const float* __restrict__ x,
                const float* __restrict__ theta,
                float* __restrict__ ws) {
  __shared__ half8 s_keys[KCHUNK];            // [key][wire0-3, 0,0,0,0]  (4 KB)
  __shared__ _Float16 s_kvT[5 * KVT_STRIDE];  // perm key order; row 4 = ones (2.6 KB)

  const int bid = blockIdx.x;
  const int rb  = bid & 15;
  const int bh  = (bid >> 4) & 31;
  const int ih  = bid >> 9;
  const int b   = bh >> 1;
  const int h   = bh & 1;
  const int t   = threadIdx.x;

  const float4 th = ((const float4*)theta)[h];
  const float4* x4 = (const float4*)x;        // element (b*SS+s)*2 + h

  // --- stage this block's 256 keys (1 per thread) ---
  {
    const int s = ih * KCHUNK + t;
    float4 xr = x4[(size_t)(b * SS + s) * 2 + h];
    float c0 = __cosf(xr.x + th.x), c1 = __cosf(xr.y + th.y);
    float c2 = __cosf(xr.z + th.z), c3 = __cosf(xr.w + th.w);
    const _Float16 z = (_Float16)0.0f;
    half8 v = {(_Float16)c0, (_Float16)c1, (_Float16)c2, (_Float16)c3, z, z, z, z};
    s_keys[t] = v;
    const int q = t & 15;                     // perm: swap bits 2<->3
    const int pos = (t & ~15) | ((q & 3) | ((q & 4) << 1) | ((q & 8) >> 1));
    s_kvT[0 * KVT_STRIDE + pos] = (_Float16)c0;
    s_kvT[1 * KVT_STRIDE + pos] = (_Float16)c1;
    s_kvT[2 * KVT_STRIDE + pos] = (_Float16)c2;
    s_kvT[3 * KVT_STRIDE + pos] = (_Float16)c3;
  }
  for (int i = t; i < KVT_STRIDE; i += THREADS)
    s_kvT[4 * KVT_STRIDE + i] = (_Float16)1.0f;   // denominator column

  // --- per-lane query (QK B-operand), loaded from global (pre-sync OK) ---
  const int lane = t & 63;
  const int wv   = t >> 6;          // wave -> 32-row tile
  const int g    = lane >> 5;       // half-wave
  const int n    = lane & 31;       // row within tile / output col in PV
  const int row  = rb * RPB + wv * 32 + n;

  const float KS  = 0.72134752044448170367f;  // 0.5 * log2(e)
  const float scl = g ? 0.0f : KS;
  float4 xq = x4[(size_t)(b * SS + row) * 2 + h];
  const _Float16 z = (_Float16)0.0f;
  half8 bq = {(_Float16)(__cosf(xq.x + th.x) * scl),
              (_Float16)(__cosf(xq.y + th.y) * scl),
              (_Float16)(__cosf(xq.z + th.z) * scl),
              (_Float16)(__cosf(xq.w + th.w) * scl), z, z, z, z};
  __syncthreads();

  // PV B-operand pointer: row min(n,4) of kv^T (n>=5 -> ones, cols ignored)
  const _Float16* bb = s_kvT + (n < 4 ? n : 4) * KVT_STRIDE + 8 * g;

  floatx16 o  = {0,0,0,0,0,0,0,0,0,0,0,0,0,0,0,0};
  const floatx16 zf = {0,0,0,0,0,0,0,0,0,0,0,0,0,0,0,0};

#pragma unroll
  for (int kt = 0; kt < NITER; ++kt) {
    // QK A: A[m=key n][k=8g+j]; k<4 real, rest finite don't-care (B zero)
    half8 a  = s_keys[kt * 32 + n];
    half8 b1 = *(const half8*)(bb + kt * 32);        // PV1: perm keys 0-15
    half8 b2 = *(const half8*)(bb + kt * 32 + 16);   // PV2: perm keys 16-31

    // scores C[key m][row n], m=(reg&3)+8*(reg>>2)+4g, pre-scaled for exp2
    floatx16 c = __builtin_amdgcn_mfma_f32_32x32x16_f16(a, bq, zf, 0, 0, 0);

    // exp2 -> P; regs 0-7 are exactly PV1's A-fragment, regs 8-15 PV2's
    half2h p0 = pkrtz(fast_exp2(c[0]),  fast_exp2(c[1]));
    half2h p1 = pkrtz(fast_exp2(c[2]),  fast_exp2(c[3]));
    half2h p2 = pkrtz(fast_exp2(c[4]),  fast_exp2(c[5]));
    half2h p3 = pkrtz(fast_exp2(c[6]),  fast_exp2(c[7]));
    half2h p4 = pkrtz(fast_exp2(c[8]),  fast_exp2(c[9]));
    half2h p5 = pkrtz(fast_exp2(c[10]), fast_exp2(c[11]));
    half2h p6 = pkrtz(fast_exp2(c[12]), fast_exp2(c[13]));
    half2h p7 = pkrtz(fast_exp2(c[14]), fast_exp2(c[15]));
    half8 pa1 = {p0[0], p0[1], p1[0], p1[1], p2[0], p2[1], p3[0], p3[1]};
    half8 pa2 = {p4[0], p4[1], p5[0], p5[1], p6[0], p6[1], p7[0], p7[1]};

    o = __builtin_amdgcn_mfma_f32_32x32x16_f16(pa1, b1, o, 0, 0, 0);
    o = __builtin_amdgcn_mfma_f32_32x32x16_f16(pa2, b2, o, 0, 0, 0);
  }

  // D[row m][col n]: n<4 = numerator wires, n==4 = l. m=(reg&3)+8*(reg>>2)+4g
  if (n < 5) {
    float* wp = ws + ((size_t)(ih * 32 + bh) * SS + rb * RPB + wv * 32 + 4 * g) * 8 + n;
#pragma unroll
    for (int r = 0; r < 16; ++r) {
      const int m = (r & 3) + 8 * (r >> 2);    // + 4g folded into wp
      wp[(size_t)m * 8] = o[r];
    }
  }
}

// merge NIH partials, normalize, 8x8 out-projection + bias
__global__ __launch_bounds__(256)
void qattn_merge(const float* __restrict__ ws,
                 const float* __restrict__ w_out,
                 const float* __restrict__ b_out,
                 float* __restrict__ out) {
  const int gid = blockIdx.x * 256 + threadIdx.x;   // (b, s)
  const int b = gid >> 11;
  const int s = gid & 2047;
  float o[8];
#pragma unroll
  for (int h = 0; h < HH; ++h) {
    const int bh = b * 2 + h;
    float4 acc = make_float4(0.f, 0.f, 0.f, 0.f);
    float l = 0.f;
#pragma unroll
    for (int ih = 0; ih < NIH; ++ih) {
      const size_t idx = ((size_t)(ih * 32 + bh) * SS + s) * 8;
      float4 a = *(const float4*)(ws + idx);
      acc.x += a.x; acc.y += a.y; acc.z += a.z; acc.w += a.w;
      l += ws[idx + 4];
    }
    const float inv = 1.0f / l;
    o[h * 4 + 0] = acc.x * inv;
    o[h * 4 + 1] = acc.y * inv;
    o[h * 4 + 2] = acc.z * inv;
    o[h * 4 + 3] = acc.w * inv;
  }
  float r[8];
#pragma unroll
  for (int e = 0; e < 8; ++e) {
    float acc = b_out[e];
#pragma unroll
    for (int j = 0; j < 8; ++j) acc = fmaf(o[j], w_out[e * 8 + j], acc);
    r[e] = acc;
  }
  float* op = out + (size_t)gid * 8;
  *(float4*)op       = make_float4(r[0], r[1], r[2], r[3]);
  *(float4*)(op + 4) = make_float4(r[4], r[5], r[6], r[7]);
}

extern "C" void kernel_launch(void* const* d_in, const int* in_sizes, int n_in,
                              void* d_out, int out_size, void* d_ws, size_t ws_size,
                              hipStream_t stream) {
  const float* x     = (const float*)d_in[0];
  const float* theta = (const float*)d_in[1];
  const float* w_out = (const float*)d_in[2];
  const float* b_out = (const float*)d_in[3];
  float* out = (float*)d_out;
  (void)in_sizes; (void)n_in; (void)out_size; (void)ws_size;

  // ws: NIH*32*2048*8 floats = 16.8 MB of disjoint partials (no memset needed)
  qattn_part<<<dim3(NIH * 32 * 16), THREADS, 0, stream>>>(x, theta, (float*)d_ws);
  qattn_merge<<<dim3((BB * SS) / 256), 256, 0, stream>>>((const float*)d_ws, w_out, b_out, out);
}